// Round 6
// baseline (331.209 us; speedup 1.0000x reference)
//
#include <hip/hip_runtime.h>

#define L 2048
#define D 2048
#define NH 16
#define HD 128

typedef __attribute__((ext_vector_type(8))) _Float16 half8;
typedef __attribute__((ext_vector_type(4))) float f32x4;

__device__ __forceinline__ void gload_lds16(const void* g, void* l) {
    __builtin_amdgcn_global_load_lds(
        (const __attribute__((address_space(1))) uint32_t*)g,
        (__attribute__((address_space(3))) uint32_t*)l, 16, 0, 0);
}

// ---------------- f32 -> fp16 convert ----------------
__global__ void cvt_kernel(const float* __restrict__ in, _Float16* __restrict__ out, int n4) {
    int idx = blockIdx.x * blockDim.x + threadIdx.x;
    int stride = gridDim.x * blockDim.x;
    for (int i = idx; i < n4; i += stride) {
        float4 v = reinterpret_cast<const float4*>(in)[i];
        union { _Float16 h[4]; uint2 u; } pk;
        pk.h[0] = (_Float16)v.x; pk.h[1] = (_Float16)v.y;
        pk.h[2] = (_Float16)v.z; pk.h[3] = (_Float16)v.w;
        reinterpret_cast<uint2*>(out)[i] = pk.u;
    }
}

// ---------------- NT GEMM: C[M][N] = A[M][K] * B[N][K]^T ----------------
// LDS-staged (global_load_lds w=16), double-buffered, 2-phase pipeline.
// 128x128 block tile, 4 waves 2x2, 4x4 16x16x32 fragments per wave, BK=32.
// EPI 0: scatter qkv. q -> qk[0][h][l][d] linear; k -> qk[1][h][l][d^((l&7)<<3)]
//        (XOR-swizzled for attn LDS staging); v -> vt[h][d][l] linear.
// EPI 1: write f32 C row-major to Cout
template <int EPI>
__global__ __launch_bounds__(256) void gemm_nt(
    const _Float16* __restrict__ A, const _Float16* __restrict__ B,
    float* __restrict__ Cout, _Float16* __restrict__ qk, _Float16* __restrict__ vt,
    int M, int N, int K)
{
    __shared__ __align__(16) _Float16 Asm[2][128 * 32];   // 2 x 8 KB
    __shared__ __align__(16) _Float16 Bsm[2][128 * 32];   // 2 x 8 KB
    int tid = threadIdx.x;
    int wid = tid >> 6;
    int lane = tid & 63;
    int wr = wid >> 1, wc = wid & 1;
    int m0 = blockIdx.x * 128;
    int n0 = blockIdx.y * 128;
    int lr = lane & 15;   // row/col within 16
    int lg = lane >> 4;   // group 0..3

    // staging source: thread tid covers tile rows {tid>>2, 64+(tid>>2)}, byte col (tid&3)*16
    const char* Asrc = (const char*)(A + (size_t)(m0 + (tid >> 2)) * K) + (tid & 3) * 16;
    const char* Bsrc = (const char*)(B + (size_t)(n0 + (tid >> 2)) * K) + (tid & 3) * 16;
    size_t rowskip = (size_t)64 * K * 2;   // 64 rows of source, bytes

    auto stage = [&](int k0, int b) {
        const char* as = Asrc + (size_t)k0 * 2;
        const char* bs = Bsrc + (size_t)k0 * 2;
        char* ad = (char*)&Asm[b][0] + wid * 1024;   // + lane*16 by hardware
        char* bd = (char*)&Bsm[b][0] + wid * 1024;
        gload_lds16(as, ad);
        gload_lds16(as + rowskip, ad + 4096);
        gload_lds16(bs, bd);
        gload_lds16(bs + rowskip, bd + 4096);
    };

    f32x4 acc[4][4];
#pragma unroll
    for (int i = 0; i < 4; i++)
#pragma unroll
        for (int j = 0; j < 4; j++)
            acc[i][j] = (f32x4){0.f, 0.f, 0.f, 0.f};

    int NT = K / 32;
    stage(0, 0);
    asm volatile("s_waitcnt vmcnt(0)" ::: "memory");
    __syncthreads();

    for (int t = 0; t < NT; t++) {
        int cur = t & 1;
        if (t + 1 < NT) stage((t + 1) * 32, cur ^ 1);

        const char* ab = (const char*)&Asm[cur][0] + (wr * 64 + lr) * 64 + lg * 16;
        const char* bb = (const char*)&Bsm[cur][0] + (wc * 64 + lr) * 64 + lg * 16;
        half8 a[4], b[4];
#pragma unroll
        for (int i = 0; i < 4; i++) a[i] = *(const half8*)(ab + i * 1024);
#pragma unroll
        for (int j = 0; j < 4; j++) b[j] = *(const half8*)(bb + j * 1024);
#pragma unroll
        for (int i = 0; i < 4; i++)
#pragma unroll
            for (int j = 0; j < 4; j++)
                acc[i][j] = __builtin_amdgcn_mfma_f32_16x16x32_f16(a[i], b[j], acc[i][j], 0, 0, 0);

        asm volatile("s_waitcnt vmcnt(0)" ::: "memory");
        __syncthreads();
    }

#pragma unroll
    for (int i = 0; i < 4; i++) {
#pragma unroll
        for (int j = 0; j < 4; j++) {
#pragma unroll
            for (int r = 0; r < 4; r++) {
                int row = m0 + wr * 64 + i * 16 + lg * 4 + r;  // C layout: row=(lane>>4)*4+reg
                int col = n0 + wc * 64 + j * 16 + lr;          //           col=lane&15
                float v = acc[i][j][r];
                if (EPI == 0) {
                    int t = col >> 11;
                    int w2 = col & 2047;
                    int h = w2 >> 7, d = w2 & 127;
                    if (t == 0) {
                        qk[(((size_t)h) * L + row) * HD + d] = (_Float16)v;
                    } else if (t == 1) {
                        int dsw = d ^ ((row & 7) << 3);   // pre-swizzle for attn K staging
                        qk[(((size_t)NH + h) * L + row) * HD + dsw] = (_Float16)v;
                    } else {
                        vt[((size_t)h * HD + d) * L + row] = (_Float16)v;
                    }
                } else {
                    Cout[(size_t)row * N + col] = v;
                }
            }
        }
    }
}

// ---------------- fused RMSNorm + RoPE on q and k planes (in place) ----------------
__global__ void norm_rope(_Float16* __restrict__ qk) {
    int wid = threadIdx.x >> 6, lane = threadIdx.x & 63;
    int row = blockIdx.x * 4 + wid;      // 0 .. 2*NH*L-1
    int l = row & (L - 1);
    int th = row >> 11;                  // t*NH + h, 0..31
    _Float16* p = qk + ((size_t)th * L + l) * HD + lane * 2;
    float x0 = (float)p[0];
    float x1 = (float)p[1];
    float ss = x0 * x0 + x1 * x1;
#pragma unroll
    for (int off = 1; off < 64; off <<= 1) ss += __shfl_xor(ss, off);
    float r = rsqrtf(ss * (1.0f / 128.0f) + 1e-5f);
    float n0 = x0 * r, n1 = x1 * r;
    int i = (th >= NH) ? (lane ^ ((l & 7) << 2)) : lane;   // swizzle-aware pair index
    float freq = expf(-(float)(2 * i) * (1.0f / 128.0f) * logf(100000.0f));
    float ang = (float)l * freq;
    float s, c;
    sincosf(ang, &s, &c);
    p[0] = (_Float16)(n1 * c - n0 * s);
    p[1] = (_Float16)(n1 * s + n0 * c);
}

// ---------------- causal flash attention, v5: KV-split ----------------
// Static-offset softmax means partitions combine by pure ADDITION of
// unnormalized O (f32) and lsum. Each (h, qt) is split into partitions of
// up to 8 KV tiles (512 positions); 1280 blocks total, each <= 8 tiles ->
// 4 blocks/CU resident (40KB LDS), ~16 waves/CU vs v4's ~4.
// Partials atomically added into f32 Of[L][D] and Ls[NH][L] (pre-zeroed);
// normalize_o then divides and converts to fp16.
__global__ __launch_bounds__(256, 4) void attn_kernel(
    const _Float16* __restrict__ qk, const _Float16* __restrict__ vt,
    float* __restrict__ Of, float* __restrict__ Ls)
{
    __shared__ __align__(16) _Float16 Kt[2][64 * HD];     // 2 x 16 KB
    __shared__ __align__(16) _Float16 plds[4][16 * 64];   // 8 KB
    int wid = threadIdx.x >> 6, lane = threadIdx.x & 63;
    int bid = blockIdx.x;
    int h = bid & 15;
    int w = 79 - (bid >> 4);             // big partitions launch first
    // decode w -> (qt, p): bands of 8 qts with 1,2,3,4 partitions each
    int qt, p;
    if (w < 8)       { qt = w;                p = 0; }
    else if (w < 24) { int u = w - 8;  qt = 8 + (u >> 1);  p = u & 1; }
    else if (w < 48) { int u = w - 24; qt = 16 + u / 3;    p = u - 3 * (u / 3); }
    else             { int u = w - 48; qt = 24 + (u >> 2); p = u & 3; }
    int t0 = p * 8;
    int t1 = min(t0 + 8, qt + 1);
    int q0 = qt * 64 + wid * 16;
    int lr = lane & 15, lg = lane >> 4;

    const _Float16* qn = qk + (size_t)h * L * HD;              // q plane
    const _Float16* kn = qk + ((size_t)(NH + h) * L) * HD;     // k plane (swizzled)
    const _Float16* vp = vt + (size_t)h * HD * L;              // v^T plane

    half8 qa[4];
#pragma unroll
    for (int kk = 0; kk < 4; kk++)
        qa[kk] = *reinterpret_cast<const half8*>(qn + (size_t)(q0 + lr) * HD + kk * 32 + lg * 8);

    f32x4 oacc[8];
#pragma unroll
    for (int jo = 0; jo < 8; jo++) oacc[jo] = (f32x4){0.f, 0.f, 0.f, 0.f};
    float lsum[4] = {0.f, 0.f, 0.f, 0.f};

    const float scale = 0.08838834764831845f;  // 1/sqrt(128)
    const float OFF = 4.0f;                    // static exp offset (absolute)
    char* pbase = (char*)&plds[wid][0];

    // ---- stage K tile t into buffer b (16 KB contiguous copy, wave w: 4 KB) ----
    auto stage_k = [&](int t, int b) {
        const char* src = (const char*)(kn + (size_t)t * 64 * HD) + wid * 4096 + lane * 16;
        char* dst = (char*)&Kt[b][0] + wid * 4096;
#pragma unroll
        for (int i = 0; i < 4; i++)
            gload_lds16(src + i * 1024, dst + i * 1024);
    };

    stage_k(t0, 0);
    __syncthreads();

    for (int t = t0; t < t1; t++) {
        int cur = (t - t0) & 1;
        int kv0 = t * 64;

        // ---- V register loads FIRST (oldest in vmcnt queue) ----
        half8 vr0[8], vr1[8];
#pragma unroll
        for (int jo = 0; jo < 8; jo++) {
            const _Float16* vrow = vp + (size_t)(jo * 16 + lr) * L + kv0 + lg * 8;
            vr0[jo] = *reinterpret_cast<const half8*>(vrow);
            vr1[jo] = *reinterpret_cast<const half8*>(vrow + 32);
        }
        __builtin_amdgcn_sched_barrier(0);   // pin: V loads before stage

        // ---- stage next K tile (stays in flight across this tile) ----
        if (t + 1 < t1) stage_k(t + 1, cur ^ 1);

        // ---- S = Q K^T from LDS (swizzled ds_read_b128) ----
        f32x4 sC[4];
#pragma unroll
        for (int jt = 0; jt < 4; jt++) sC[jt] = (f32x4){0.f, 0.f, 0.f, 0.f};
        const char* kb = (const char*)&Kt[cur][0];
#pragma unroll
        for (int kk = 0; kk < 4; kk++) {
#pragma unroll
            for (int jt = 0; jt < 4; jt++) {
                half8 bk = *(const half8*)(kb + (jt * 16 + lr) * 256 +
                                           ((kk * 64 + lg * 16) ^ ((lr & 7) << 4)));
                sC[jt] = __builtin_amdgcn_mfma_f32_16x16x32_f16(qa[kk], bk, sC[jt], 0, 0, 0);
            }
        }

        // ---- p = exp(s*scale - OFF), row-sum per lane, bounce via LDS ----
        bool diag = (t == qt);
#pragma unroll
        for (int jt = 0; jt < 4; jt++) {
#pragma unroll
            for (int r = 0; r < 4; r++) {
                int row = lg * 4 + r;
                float pv = __expf(sC[jt][r] * scale - OFF);
                if (diag && (kv0 + jt * 16 + lr > q0 + row)) pv = 0.f;
                lsum[r] += pv;
                int colb = (lr + 16 * jt) * 2;
                *(_Float16*)(pbase + row * 128 + (colb ^ ((row & 7) << 4))) = (_Float16)pv;
            }
        }

        // ---- O += P V (PV waits only for V loads; stage stays outstanding) ----
#pragma unroll
        for (int kk2 = 0; kk2 < 2; kk2++) {
            half8 pa = *(const half8*)(pbase + lr * 128 +
                                       ((kk2 * 64 + lg * 16) ^ ((lr & 7) << 4)));
#pragma unroll
            for (int jo = 0; jo < 8; jo++) {
                half8 bv = (kk2 == 0) ? vr0[jo] : vr1[jo];
                oacc[jo] = __builtin_amdgcn_mfma_f32_16x16x32_f16(pa, bv, oacc[jo], 0, 0, 0);
            }
        }
        __syncthreads();
    }

    // ---- lsum: 16-lane group reduce, one lane adds per row ----
#pragma unroll
    for (int r = 0; r < 4; r++) {
#pragma unroll
        for (int off = 1; off < 16; off <<= 1) lsum[r] += __shfl_xor(lsum[r], off);
    }
    if (lr == 0) {
#pragma unroll
        for (int r = 0; r < 4; r++)
            atomicAdd(&Ls[(size_t)h * L + q0 + lg * 4 + r], lsum[r]);
    }

    // ---- unnormalized O: atomic f32 add into Of[L][D] ----
#pragma unroll
    for (int jo = 0; jo < 8; jo++) {
#pragma unroll
        for (int r = 0; r < 4; r++) {
            int row = q0 + lg * 4 + r;
            int col = h * HD + jo * 16 + lr;
            atomicAdd(&Of[(size_t)row * D + col], oacc[jo][r]);
        }
    }
}

// ---------------- normalize: aoh = fp16(Of / Ls) ----------------
__global__ void normalize_o(const float* __restrict__ Of, const float* __restrict__ Ls,
                            _Float16* __restrict__ out) {
    int i4 = blockIdx.x * blockDim.x + threadIdx.x;   // over L*D/4
    int row = i4 >> 9;                                 // D/4 = 512
    int c4 = (i4 & 511) << 2;
    int h = c4 >> 7;
    f32x4 v = reinterpret_cast<const f32x4*>(Of)[i4];
    float inv = 1.0f / Ls[(size_t)h * L + row];
    union { _Float16 h4[4]; uint2 u; } pk;
#pragma unroll
    for (int j = 0; j < 4; j++) pk.h4[j] = (_Float16)(v[j] * inv);
    reinterpret_cast<uint2*>(out)[i4] = pk.u;
}

extern "C" void kernel_launch(void* const* d_in, const int* in_sizes, int n_in,
                              void* d_out, int out_size, void* d_ws, size_t ws_size,
                              hipStream_t stream) {
    const float* x = (const float*)d_in[0];
    const float* wqkv = (const float*)d_in[1];
    const float* wout = (const float*)d_in[2];
    // block_mask (d_in[3]) is tril(ones) == causal; handled analytically.

    _Float16* ws = (_Float16*)d_ws;
    _Float16* xh = ws;                                    // L*D
    _Float16* wqkvh = xh + (size_t)L * D;                 // 3*D*D
    _Float16* wouth = wqkvh + (size_t)3 * D * D;          // D*D
    _Float16* qkh = wouth + (size_t)D * D;                // 2*NH*L*HD
    _Float16* vth = qkh + (size_t)2 * NH * L * HD;        // NH*HD*L
    _Float16* aoh = vth + (size_t)NH * HD * L;            // L*D
    float* Of = (float*)(aoh + (size_t)L * D);            // L*D f32
    float* Ls = Of + (size_t)L * D;                       // NH*L f32
    // total ~92.5 MB of d_ws

    hipMemsetAsync(Of, 0, ((size_t)L * D + NH * L) * sizeof(float), stream);

    cvt_kernel<<<2048, 256, 0, stream>>>(x, xh, L * D / 4);
    cvt_kernel<<<2048, 256, 0, stream>>>(wqkv, wqkvh, 3 * D * D / 4);
    cvt_kernel<<<2048, 256, 0, stream>>>(wout, wouth, D * D / 4);

    gemm_nt<0><<<dim3(L / 128, 3 * D / 128), 256, 0, stream>>>(
        xh, wqkvh, nullptr, qkh, vth, L, 3 * D, D);

    norm_rope<<<2 * NH * L / 4, 256, 0, stream>>>(qkh);

    attn_kernel<<<1280, 256, 0, stream>>>(qkh, vth, Of, Ls);

    normalize_o<<<L * D / 4 / 256, 256, 0, stream>>>(Of, Ls, aoh);

    gemm_nt<1><<<dim3(L / 128, D / 128), 256, 0, stream>>>(
        aoh, wouth, (float*)d_out, nullptr, nullptr, L, D, D);
}

// Round 7
// 239.617 us; speedup vs baseline: 1.3822x; 1.3822x over previous
//
#include <hip/hip_runtime.h>

#define L 2048
#define D 2048
#define NH 16
#define HD 128

typedef __attribute__((ext_vector_type(8))) _Float16 half8;
typedef __attribute__((ext_vector_type(4))) float f32x4;

__device__ __forceinline__ void gload_lds16(const void* g, void* l) {
    __builtin_amdgcn_global_load_lds(
        (const __attribute__((address_space(1))) uint32_t*)g,
        (__attribute__((address_space(3))) uint32_t*)l, 16, 0, 0);
}

// ---------------- f32 -> fp16 convert ----------------
__global__ void cvt_kernel(const float* __restrict__ in, _Float16* __restrict__ out, int n4) {
    int idx = blockIdx.x * blockDim.x + threadIdx.x;
    int stride = gridDim.x * blockDim.x;
    for (int i = idx; i < n4; i += stride) {
        float4 v = reinterpret_cast<const float4*>(in)[i];
        union { _Float16 h[4]; uint2 u; } pk;
        pk.h[0] = (_Float16)v.x; pk.h[1] = (_Float16)v.y;
        pk.h[2] = (_Float16)v.z; pk.h[3] = (_Float16)v.w;
        reinterpret_cast<uint2*>(out)[i] = pk.u;
    }
}

// ---------------- NT GEMM: C[M][N] = A[M][K] * B[N][K]^T ----------------
// LDS-staged (global_load_lds w=16), double-buffered, 2-phase pipeline.
// 128x128 block tile, 4 waves 2x2, 4x4 16x16x32 fragments per wave, BK=32.
// EPI 0: scatter qkv. q -> qk[0][h][l][d] linear; k -> qk[1][h][l][d^((l&7)<<3)]
//        (XOR-swizzled for attn LDS staging); v -> vt[h][d][l] linear.
// EPI 1: write f32 C row-major to Cout
template <int EPI>
__global__ __launch_bounds__(256) void gemm_nt(
    const _Float16* __restrict__ A, const _Float16* __restrict__ B,
    float* __restrict__ Cout, _Float16* __restrict__ qk, _Float16* __restrict__ vt,
    int M, int N, int K)
{
    __shared__ __align__(16) _Float16 Asm[2][128 * 32];   // 2 x 8 KB
    __shared__ __align__(16) _Float16 Bsm[2][128 * 32];   // 2 x 8 KB
    int tid = threadIdx.x;
    int wid = tid >> 6;
    int lane = tid & 63;
    int wr = wid >> 1, wc = wid & 1;
    int m0 = blockIdx.x * 128;
    int n0 = blockIdx.y * 128;
    int lr = lane & 15;   // row/col within 16
    int lg = lane >> 4;   // group 0..3

    // staging source: thread tid covers tile rows {tid>>2, 64+(tid>>2)}, byte col (tid&3)*16
    const char* Asrc = (const char*)(A + (size_t)(m0 + (tid >> 2)) * K) + (tid & 3) * 16;
    const char* Bsrc = (const char*)(B + (size_t)(n0 + (tid >> 2)) * K) + (tid & 3) * 16;
    size_t rowskip = (size_t)64 * K * 2;   // 64 rows of source, bytes

    auto stage = [&](int k0, int b) {
        const char* as = Asrc + (size_t)k0 * 2;
        const char* bs = Bsrc + (size_t)k0 * 2;
        char* ad = (char*)&Asm[b][0] + wid * 1024;   // + lane*16 by hardware
        char* bd = (char*)&Bsm[b][0] + wid * 1024;
        gload_lds16(as, ad);
        gload_lds16(as + rowskip, ad + 4096);
        gload_lds16(bs, bd);
        gload_lds16(bs + rowskip, bd + 4096);
    };

    f32x4 acc[4][4];
#pragma unroll
    for (int i = 0; i < 4; i++)
#pragma unroll
        for (int j = 0; j < 4; j++)
            acc[i][j] = (f32x4){0.f, 0.f, 0.f, 0.f};

    int NT = K / 32;
    stage(0, 0);
    asm volatile("s_waitcnt vmcnt(0)" ::: "memory");
    __syncthreads();

    for (int t = 0; t < NT; t++) {
        int cur = t & 1;
        if (t + 1 < NT) stage((t + 1) * 32, cur ^ 1);

        const char* ab = (const char*)&Asm[cur][0] + (wr * 64 + lr) * 64 + lg * 16;
        const char* bb = (const char*)&Bsm[cur][0] + (wc * 64 + lr) * 64 + lg * 16;
        half8 a[4], b[4];
#pragma unroll
        for (int i = 0; i < 4; i++) a[i] = *(const half8*)(ab + i * 1024);
#pragma unroll
        for (int j = 0; j < 4; j++) b[j] = *(const half8*)(bb + j * 1024);
#pragma unroll
        for (int i = 0; i < 4; i++)
#pragma unroll
            for (int j = 0; j < 4; j++)
                acc[i][j] = __builtin_amdgcn_mfma_f32_16x16x32_f16(a[i], b[j], acc[i][j], 0, 0, 0);

        asm volatile("s_waitcnt vmcnt(0)" ::: "memory");
        __syncthreads();
    }

#pragma unroll
    for (int i = 0; i < 4; i++) {
#pragma unroll
        for (int j = 0; j < 4; j++) {
#pragma unroll
            for (int r = 0; r < 4; r++) {
                int row = m0 + wr * 64 + i * 16 + lg * 4 + r;  // C layout: row=(lane>>4)*4+reg
                int col = n0 + wc * 64 + j * 16 + lr;          //           col=lane&15
                float v = acc[i][j][r];
                if (EPI == 0) {
                    int t = col >> 11;
                    int w2 = col & 2047;
                    int h = w2 >> 7, d = w2 & 127;
                    if (t == 0) {
                        qk[(((size_t)h) * L + row) * HD + d] = (_Float16)v;
                    } else if (t == 1) {
                        int dsw = d ^ ((row & 7) << 3);   // pre-swizzle for attn K staging
                        qk[(((size_t)NH + h) * L + row) * HD + dsw] = (_Float16)v;
                    } else {
                        vt[((size_t)h * HD + d) * L + row] = (_Float16)v;
                    }
                } else {
                    Cout[(size_t)row * N + col] = v;
                }
            }
        }
    }
}

// ---------------- fused RMSNorm + RoPE on q and k planes (in place) ----------------
__global__ void norm_rope(_Float16* __restrict__ qk) {
    int wid = threadIdx.x >> 6, lane = threadIdx.x & 63;
    int row = blockIdx.x * 4 + wid;      // 0 .. 2*NH*L-1
    int l = row & (L - 1);
    int th = row >> 11;                  // t*NH + h, 0..31
    _Float16* p = qk + ((size_t)th * L + l) * HD + lane * 2;
    float x0 = (float)p[0];
    float x1 = (float)p[1];
    float ss = x0 * x0 + x1 * x1;
#pragma unroll
    for (int off = 1; off < 64; off <<= 1) ss += __shfl_xor(ss, off);
    float r = rsqrtf(ss * (1.0f / 128.0f) + 1e-5f);
    float n0 = x0 * r, n1 = x1 * r;
    int i = (th >= NH) ? (lane ^ ((l & 7) << 2)) : lane;   // swizzle-aware pair index
    float freq = expf(-(float)(2 * i) * (1.0f / 128.0f) * logf(100000.0f));
    float ang = (float)l * freq;
    float s, c;
    sincosf(ang, &s, &c);
    p[0] = (_Float16)(n1 * c - n0 * s);
    p[1] = (_Float16)(n1 * s + n0 * c);
}

// ---------------- causal flash attention, v6: persistent + work queue ----------------
// Items = (h, qt, half): each (h,qt)'s KV range split into two contiguous
// halves (<=16 tiles). 1024 items, decoded BIG-FIRST. 768 persistent blocks
// (3/CU resident, 12 waves/CU) pull items from an atomic counter -> dynamic
// LPT balance (v4's static assignment left CUs idle: 13.5% occupancy).
// Halves write SEPARATE fp16 partial buffers (no atomics, no races);
// normalize_o combines: O = (Oa+Ob)/(La+Lb). Static-offset softmax makes
// partial combination pure addition. Inner tile body identical to v4.
__global__ __launch_bounds__(256, 2) void attn_kernel(
    const _Float16* __restrict__ qk, const _Float16* __restrict__ vt,
    _Float16* __restrict__ Oab, float* __restrict__ Lab, int* __restrict__ cnt)
{
    __shared__ __align__(16) _Float16 Kt[2][64 * HD];     // 2 x 16 KB
    __shared__ __align__(16) _Float16 plds[4][16 * 64];   // 8 KB
    __shared__ int sh_i;
    int wid = threadIdx.x >> 6, lane = threadIdx.x & 63;
    int lr = lane & 15, lg = lane >> 4;

    const float scale = 0.08838834764831845f;  // 1/sqrt(128)
    const float OFF = 4.0f;                    // static exp offset (absolute)
    char* pbase = (char*)&plds[wid][0];

    for (;;) {
        __syncthreads();   // protects sh_i rewrite + Kt reuse across items
        if (threadIdx.x == 0) sh_i = atomicAdd(cnt, 1);
        __syncthreads();
        int item = sh_i;
        if (item >= 1024) return;

        // decode big-first: qt descending; 32 items (16h x 2half) per qt
        int qt = 31 - (item >> 5);
        int h = (item >> 1) & 15;
        int half = item & 1;
        int n = qt + 1;
        int mid = (n + 1) >> 1;
        int t0 = half ? mid : 0;
        int t1 = half ? n : mid;
        int q0 = qt * 64 + wid * 16;

        const _Float16* qn = qk + (size_t)h * L * HD;              // q plane
        const _Float16* kn = qk + ((size_t)(NH + h) * L) * HD;     // k plane (swizzled)
        const _Float16* vp = vt + (size_t)h * HD * L;              // v^T plane

        half8 qa[4];
#pragma unroll
        for (int kk = 0; kk < 4; kk++)
            qa[kk] = *reinterpret_cast<const half8*>(qn + (size_t)(q0 + lr) * HD + kk * 32 + lg * 8);

        f32x4 oacc[8];
#pragma unroll
        for (int jo = 0; jo < 8; jo++) oacc[jo] = (f32x4){0.f, 0.f, 0.f, 0.f};
        float lsum[4] = {0.f, 0.f, 0.f, 0.f};

        auto stage_k = [&](int t, int b) {
            const char* src = (const char*)(kn + (size_t)t * 64 * HD) + wid * 4096 + lane * 16;
            char* dst = (char*)&Kt[b][0] + wid * 4096;
#pragma unroll
            for (int i = 0; i < 4; i++)
                gload_lds16(src + i * 1024, dst + i * 1024);
        };

        if (t0 < t1) {
            stage_k(t0, 0);
            __syncthreads();

            for (int t = t0; t < t1; t++) {
                int cur = (t - t0) & 1;
                int kv0 = t * 64;

                // ---- V register loads FIRST (oldest in vmcnt queue) ----
                half8 vr0[8], vr1[8];
#pragma unroll
                for (int jo = 0; jo < 8; jo++) {
                    const _Float16* vrow = vp + (size_t)(jo * 16 + lr) * L + kv0 + lg * 8;
                    vr0[jo] = *reinterpret_cast<const half8*>(vrow);
                    vr1[jo] = *reinterpret_cast<const half8*>(vrow + 32);
                }
                __builtin_amdgcn_sched_barrier(0);   // pin: V loads before stage

                // ---- stage next K tile (stays in flight across this tile) ----
                if (t + 1 < t1) stage_k(t + 1, cur ^ 1);

                // ---- S = Q K^T from LDS (swizzled ds_read_b128) ----
                f32x4 sC[4];
#pragma unroll
                for (int jt = 0; jt < 4; jt++) sC[jt] = (f32x4){0.f, 0.f, 0.f, 0.f};
                const char* kb = (const char*)&Kt[cur][0];
#pragma unroll
                for (int kk = 0; kk < 4; kk++) {
#pragma unroll
                    for (int jt = 0; jt < 4; jt++) {
                        half8 bk = *(const half8*)(kb + (jt * 16 + lr) * 256 +
                                                   ((kk * 64 + lg * 16) ^ ((lr & 7) << 4)));
                        sC[jt] = __builtin_amdgcn_mfma_f32_16x16x32_f16(qa[kk], bk, sC[jt], 0, 0, 0);
                    }
                }

                // ---- p = exp(s*scale - OFF), row-sum per lane, bounce via LDS ----
                bool diag = (t == qt);
#pragma unroll
                for (int jt = 0; jt < 4; jt++) {
#pragma unroll
                    for (int r = 0; r < 4; r++) {
                        int row = lg * 4 + r;
                        float pv = __expf(sC[jt][r] * scale - OFF);
                        if (diag && (kv0 + jt * 16 + lr > q0 + row)) pv = 0.f;
                        lsum[r] += pv;
                        int colb = (lr + 16 * jt) * 2;
                        *(_Float16*)(pbase + row * 128 + (colb ^ ((row & 7) << 4))) = (_Float16)pv;
                    }
                }

                // ---- O += P V (PV waits only for V loads; stage stays outstanding) ----
#pragma unroll
                for (int kk2 = 0; kk2 < 2; kk2++) {
                    half8 pa = *(const half8*)(pbase + lr * 128 +
                                               ((kk2 * 64 + lg * 16) ^ ((lr & 7) << 4)));
#pragma unroll
                    for (int jo = 0; jo < 8; jo++) {
                        half8 bv = (kk2 == 0) ? vr0[jo] : vr1[jo];
                        oacc[jo] = __builtin_amdgcn_mfma_f32_16x16x32_f16(pa, bv, oacc[jo], 0, 0, 0);
                    }
                }
                __syncthreads();
            }
        }

        // ---- lsum: 16-lane group reduce; one lane writes per row ----
#pragma unroll
        for (int r = 0; r < 4; r++) {
#pragma unroll
            for (int off = 1; off < 16; off <<= 1) lsum[r] += __shfl_xor(lsum[r], off);
        }
        if (lr == 0) {
#pragma unroll
            for (int r = 0; r < 4; r++)
                Lab[((size_t)half * NH + h) * L + q0 + lg * 4 + r] = lsum[r];
        }

        // ---- write unnormalized partial O tile (fp16, owned exclusively) ----
        _Float16* ob = Oab + (size_t)half * L * D;
#pragma unroll
        for (int jo = 0; jo < 8; jo++) {
#pragma unroll
            for (int r = 0; r < 4; r++) {
                int row = q0 + lg * 4 + r;
                int col = h * HD + jo * 16 + lr;
                ob[(size_t)row * D + col] = (_Float16)oacc[jo][r];
            }
        }
    }
}

// ---------------- normalize: aoh = fp16((Oa+Ob) / (La+Lb)) ----------------
__global__ void normalize_o(const _Float16* __restrict__ Oab, const float* __restrict__ Lab,
                            _Float16* __restrict__ out) {
    int i8 = blockIdx.x * blockDim.x + threadIdx.x;   // over L*D/8
    int row = i8 >> 8;                                 // D/8 = 256
    int c8 = (i8 & 255) << 3;
    int h = c8 >> 7;
    half8 a = reinterpret_cast<const half8*>(Oab)[i8];
    half8 b = reinterpret_cast<const half8*>(Oab + (size_t)L * D)[i8];
    float la = Lab[(size_t)h * L + row];
    float lb = Lab[(size_t)(NH + h) * L + row];
    float inv = 1.0f / (la + lb);
    half8 o;
#pragma unroll
    for (int j = 0; j < 8; j++) o[j] = (_Float16)(((float)a[j] + (float)b[j]) * inv);
    reinterpret_cast<half8*>(out)[i8] = o;
}

extern "C" void kernel_launch(void* const* d_in, const int* in_sizes, int n_in,
                              void* d_out, int out_size, void* d_ws, size_t ws_size,
                              hipStream_t stream) {
    const float* x = (const float*)d_in[0];
    const float* wqkv = (const float*)d_in[1];
    const float* wout = (const float*)d_in[2];
    // block_mask (d_in[3]) is tril(ones) == causal; handled analytically.

    _Float16* ws = (_Float16*)d_ws;
    _Float16* xh = ws;                                    // L*D
    _Float16* wqkvh = xh + (size_t)L * D;                 // 3*D*D
    _Float16* wouth = wqkvh + (size_t)3 * D * D;          // D*D
    _Float16* qkh = wouth + (size_t)D * D;                // 2*NH*L*HD
    _Float16* vth = qkh + (size_t)2 * NH * L * HD;        // NH*HD*L
    _Float16* aoh = vth + (size_t)NH * HD * L;            // L*D
    _Float16* Oab = aoh + (size_t)L * D;                  // 2*L*D fp16 partials
    float* Lab = (float*)(Oab + (size_t)2 * L * D);       // 2*NH*L f32
    int* cnt = (int*)(Lab + (size_t)2 * NH * L);          // work-queue counter
    // total ~89 MB of d_ws

    hipMemsetAsync(cnt, 0, 256, stream);

    cvt_kernel<<<2048, 256, 0, stream>>>(x, xh, L * D / 4);
    cvt_kernel<<<2048, 256, 0, stream>>>(wqkv, wqkvh, 3 * D * D / 4);
    cvt_kernel<<<2048, 256, 0, stream>>>(wout, wouth, D * D / 4);

    gemm_nt<0><<<dim3(L / 128, 3 * D / 128), 256, 0, stream>>>(
        xh, wqkvh, nullptr, qkh, vth, L, 3 * D, D);

    norm_rope<<<2 * NH * L / 4, 256, 0, stream>>>(qkh);

    attn_kernel<<<768, 256, 0, stream>>>(qkh, vth, Oab, Lab, cnt);

    normalize_o<<<L * D / 8 / 256, 256, 0, stream>>>(Oab, Lab, aoh);

    gemm_nt<1><<<dim3(L / 128, D / 128), 256, 0, stream>>>(
        aoh, wouth, (float*)d_out, nullptr, nullptr, L, D, D);
}

// Round 9
// 236.346 us; speedup vs baseline: 1.4014x; 1.0138x over previous
//
#include <hip/hip_runtime.h>

#define L 2048
#define D 2048
#define NH 16
#define HD 128

typedef __attribute__((ext_vector_type(8))) _Float16 half8;
typedef __attribute__((ext_vector_type(4))) float f32x4;

__device__ __forceinline__ void gload_lds16(const void* g, void* l) {
    __builtin_amdgcn_global_load_lds(
        (const __attribute__((address_space(1))) uint32_t*)g,
        (__attribute__((address_space(3))) uint32_t*)l, 16, 0, 0);
}

// ---------------- f32 -> fp16 convert ----------------
__global__ void cvt_kernel(const float* __restrict__ in, _Float16* __restrict__ out, int n4) {
    int idx = blockIdx.x * blockDim.x + threadIdx.x;
    int stride = gridDim.x * blockDim.x;
    for (int i = idx; i < n4; i += stride) {
        float4 v = reinterpret_cast<const float4*>(in)[i];
        union { _Float16 h[4]; uint2 u; } pk;
        pk.h[0] = (_Float16)v.x; pk.h[1] = (_Float16)v.y;
        pk.h[2] = (_Float16)v.z; pk.h[3] = (_Float16)v.w;
        reinterpret_cast<uint2*>(out)[i] = pk.u;
    }
}

// ---------------- NT GEMM: C[M][N] = A[M][K] * B[N][K]^T ----------------
// LDS-staged (global_load_lds w=16), double-buffered, 2-phase pipeline.
// 128x128 block tile, 4 waves 2x2, 4x4 16x16x32 fragments per wave, BK=32.
// EPI 0: scatter qkv. q -> qk[0][h][l][d] linear; k -> qk[1][h][l][d^((l&7)<<3)]
//        (XOR-swizzled for attn LDS staging); v -> vt[h][d][l] linear.
// EPI 1: write f32 C row-major to Cout
template <int EPI>
__global__ __launch_bounds__(256) void gemm_nt(
    const _Float16* __restrict__ A, const _Float16* __restrict__ B,
    float* __restrict__ Cout, _Float16* __restrict__ qk, _Float16* __restrict__ vt,
    int M, int N, int K)
{
    __shared__ __align__(16) _Float16 Asm[2][128 * 32];   // 2 x 8 KB
    __shared__ __align__(16) _Float16 Bsm[2][128 * 32];   // 2 x 8 KB
    int tid = threadIdx.x;
    int wid = tid >> 6;
    int lane = tid & 63;
    int wr = wid >> 1, wc = wid & 1;
    int m0 = blockIdx.x * 128;
    int n0 = blockIdx.y * 128;
    int lr = lane & 15;   // row/col within 16
    int lg = lane >> 4;   // group 0..3

    // staging source: thread tid covers tile rows {tid>>2, 64+(tid>>2)}, byte col (tid&3)*16
    const char* Asrc = (const char*)(A + (size_t)(m0 + (tid >> 2)) * K) + (tid & 3) * 16;
    const char* Bsrc = (const char*)(B + (size_t)(n0 + (tid >> 2)) * K) + (tid & 3) * 16;
    size_t rowskip = (size_t)64 * K * 2;   // 64 rows of source, bytes

    auto stage = [&](int k0, int b) {
        const char* as = Asrc + (size_t)k0 * 2;
        const char* bs = Bsrc + (size_t)k0 * 2;
        char* ad = (char*)&Asm[b][0] + wid * 1024;   // + lane*16 by hardware
        char* bd = (char*)&Bsm[b][0] + wid * 1024;
        gload_lds16(as, ad);
        gload_lds16(as + rowskip, ad + 4096);
        gload_lds16(bs, bd);
        gload_lds16(bs + rowskip, bd + 4096);
    };

    f32x4 acc[4][4];
#pragma unroll
    for (int i = 0; i < 4; i++)
#pragma unroll
        for (int j = 0; j < 4; j++)
            acc[i][j] = (f32x4){0.f, 0.f, 0.f, 0.f};

    int NT = K / 32;
    stage(0, 0);
    asm volatile("s_waitcnt vmcnt(0)" ::: "memory");
    __syncthreads();

    for (int t = 0; t < NT; t++) {
        int cur = t & 1;
        if (t + 1 < NT) stage((t + 1) * 32, cur ^ 1);

        const char* ab = (const char*)&Asm[cur][0] + (wr * 64 + lr) * 64 + lg * 16;
        const char* bb = (const char*)&Bsm[cur][0] + (wc * 64 + lr) * 64 + lg * 16;
        half8 a[4], b[4];
#pragma unroll
        for (int i = 0; i < 4; i++) a[i] = *(const half8*)(ab + i * 1024);
#pragma unroll
        for (int j = 0; j < 4; j++) b[j] = *(const half8*)(bb + j * 1024);
#pragma unroll
        for (int i = 0; i < 4; i++)
#pragma unroll
            for (int j = 0; j < 4; j++)
                acc[i][j] = __builtin_amdgcn_mfma_f32_16x16x32_f16(a[i], b[j], acc[i][j], 0, 0, 0);

        asm volatile("s_waitcnt vmcnt(0)" ::: "memory");
        __syncthreads();
    }

#pragma unroll
    for (int i = 0; i < 4; i++) {
#pragma unroll
        for (int j = 0; j < 4; j++) {
#pragma unroll
            for (int r = 0; r < 4; r++) {
                int row = m0 + wr * 64 + i * 16 + lg * 4 + r;  // C layout: row=(lane>>4)*4+reg
                int col = n0 + wc * 64 + j * 16 + lr;          //           col=lane&15
                float v = acc[i][j][r];
                if (EPI == 0) {
                    int t = col >> 11;
                    int w2 = col & 2047;
                    int h = w2 >> 7, d = w2 & 127;
                    if (t == 0) {
                        qk[(((size_t)h) * L + row) * HD + d] = (_Float16)v;
                    } else if (t == 1) {
                        int dsw = d ^ ((row & 7) << 3);   // pre-swizzle for attn K staging
                        qk[(((size_t)NH + h) * L + row) * HD + dsw] = (_Float16)v;
                    } else {
                        vt[((size_t)h * HD + d) * L + row] = (_Float16)v;
                    }
                } else {
                    Cout[(size_t)row * N + col] = v;
                }
            }
        }
    }
}

// ---------------- fused RMSNorm + RoPE on q and k planes (in place) ----------------
__global__ void norm_rope(_Float16* __restrict__ qk) {
    int wid = threadIdx.x >> 6, lane = threadIdx.x & 63;
    int row = blockIdx.x * 4 + wid;      // 0 .. 2*NH*L-1
    int l = row & (L - 1);
    int th = row >> 11;                  // t*NH + h, 0..31
    _Float16* p = qk + ((size_t)th * L + l) * HD + lane * 2;
    float x0 = (float)p[0];
    float x1 = (float)p[1];
    float ss = x0 * x0 + x1 * x1;
#pragma unroll
    for (int off = 1; off < 64; off <<= 1) ss += __shfl_xor(ss, off);
    float r = rsqrtf(ss * (1.0f / 128.0f) + 1e-5f);
    float n0 = x0 * r, n1 = x1 * r;
    int i = (th >= NH) ? (lane ^ ((l & 7) << 2)) : lane;   // swizzle-aware pair index
    float freq = expf(-(float)(2 * i) * (1.0f / 128.0f) * logf(100000.0f));
    float ang = (float)l * freq;
    float s, c;
    sincosf(ang, &s, &c);
    p[0] = (_Float16)(n1 * c - n0 * s);
    p[1] = (_Float16)(n1 * s + n0 * c);
}

// ---------------- causal flash attention, v8 ----------------
// v7's barrier-free loop raced: with no per-tile sync, waves drift >=1
// iteration apart and a leading wave's stage(t+2) overwrites the buffer a
// lagging wave still reads for tile t (2 buffers only). v8 keeps v7's
// counted-vmcnt pipeline but restores ONE RAW s_barrier per tile (no
// vmcnt(0)/lgkmcnt(0) drain -- that drain was v6's 20k-cyc/tile cost):
//   issue V(16) | vmcnt(16)  -> own stage(t) landed (16 V stay in flight)
//   s_barrier (raw)          -> ALL waves' stage(t) landed; all waves done
//                               reading buffer cur^1 (their QK(t-1))
//   stage(t+1) -> cur^1 (4 DMAs/wave, shared quarters, no redundancy)
//   QK(t) | softmax | vmcnt(4) -> V done, stage(t+1) outstanding | PV(t)
// Steady-state ledger: 4 ->+16V=20 ->vmcnt(16) ->+4=20 ->vmcnt(4). Never 0.
// Item framing (dynamic queue, half partials, no result atomics) unchanged.
__global__ __launch_bounds__(256, 2) void attn_kernel(
    const _Float16* __restrict__ qk, const _Float16* __restrict__ vt,
    _Float16* __restrict__ Oab, float* __restrict__ Lab, int* __restrict__ cnt)
{
    __shared__ __align__(16) _Float16 Kt[2][64 * HD];     // 2 x 16 KB (block-shared)
    __shared__ __align__(16) _Float16 plds[4][16 * 64];   // 8 KB, wave-private quarters
    __shared__ int sh_i;
    int wid = threadIdx.x >> 6, lane = threadIdx.x & 63;
    int lr = lane & 15, lg = lane >> 4;

    const float scale = 0.08838834764831845f;  // 1/sqrt(128)
    const float OFF = 4.0f;                    // static exp offset (absolute)
    char* pbase = (char*)&plds[wid][0];

    for (;;) {
        __syncthreads();   // full drain between items (protects sh_i + Kt reuse)
        if (threadIdx.x == 0) sh_i = atomicAdd(cnt, 1);
        __syncthreads();
        int item = sh_i;
        if (item >= 1024) return;

        // decode big-first: qt descending; 32 items (16h x 2half) per qt
        int qt = 31 - (item >> 5);
        int h = (item >> 1) & 15;
        int half = item & 1;
        int n = qt + 1;
        int mid = (n + 1) >> 1;
        int t0 = half ? mid : 0;
        int t1 = half ? n : mid;
        int q0 = qt * 64 + wid * 16;

        const _Float16* qn = qk + (size_t)h * L * HD;              // q plane
        const _Float16* kn = qk + ((size_t)(NH + h) * L) * HD;     // k plane (swizzled)
        const _Float16* vp = vt + (size_t)h * HD * L;              // v^T plane

        half8 qa[4];
#pragma unroll
        for (int kk = 0; kk < 4; kk++)
            qa[kk] = *reinterpret_cast<const half8*>(qn + (size_t)(q0 + lr) * HD + kk * 32 + lg * 8);

        f32x4 oacc[8];
#pragma unroll
        for (int jo = 0; jo < 8; jo++) oacc[jo] = (f32x4){0.f, 0.f, 0.f, 0.f};
        float lsum[4] = {0.f, 0.f, 0.f, 0.f};

        // per-wave QUARTER stage: wave w copies rows 16w..16w+15 (4 KB, 4 DMAs)
        auto stage_k = [&](int t, int b) {
            const char* src = (const char*)(kn + (size_t)t * 64 * HD) + wid * 4096 + lane * 16;
            char* dst = (char*)&Kt[b][0] + wid * 4096;
#pragma unroll
            for (int i = 0; i < 4; i++)
                gload_lds16(src + i * 1024, dst + i * 1024);
        };

        if (t0 < t1) {
            stage_k(t0, 0);

            for (int t = t0; t < t1; t++) {
                int cur = (t - t0) & 1;
                int kv0 = t * 64;
                bool hasnext = (t + 1 < t1);

                // ---- V register loads (16, youngest in queue) ----
                half8 vr0[8], vr1[8];
#pragma unroll
                for (int jo = 0; jo < 8; jo++) {
                    const _Float16* vrow = vp + (size_t)(jo * 16 + lr) * L + kv0 + lg * 8;
                    vr0[jo] = *reinterpret_cast<const half8*>(vrow);
                    vr1[jo] = *reinterpret_cast<const half8*>(vrow + 32);
                }
                __builtin_amdgcn_sched_barrier(0);

                // ---- own stage(t) landed (16 V remain in flight) ----
                asm volatile("s_waitcnt vmcnt(16)" ::: "memory");
                __builtin_amdgcn_sched_barrier(0);

                // ---- raw barrier, NO drain: all waves' stage(t) landed,
                //      all waves done reading buffer cur^1 ----
                __builtin_amdgcn_s_barrier();
                __builtin_amdgcn_sched_barrier(0);

                // ---- stage next K tile into cur^1 (safe after barrier) ----
                if (hasnext) stage_k(t + 1, cur ^ 1);
                __builtin_amdgcn_sched_barrier(0);

                // ---- S = Q K^T from LDS (swizzled ds_read_b128) ----
                f32x4 sC[4];
#pragma unroll
                for (int jt = 0; jt < 4; jt++) sC[jt] = (f32x4){0.f, 0.f, 0.f, 0.f};
                const char* kb = (const char*)&Kt[cur][0];
                __builtin_amdgcn_s_setprio(1);
#pragma unroll
                for (int kk = 0; kk < 4; kk++) {
#pragma unroll
                    for (int jt = 0; jt < 4; jt++) {
                        half8 bk = *(const half8*)(kb + (jt * 16 + lr) * 256 +
                                                   ((kk * 64 + lg * 16) ^ ((lr & 7) << 4)));
                        sC[jt] = __builtin_amdgcn_mfma_f32_16x16x32_f16(qa[kk], bk, sC[jt], 0, 0, 0);
                    }
                }
                __builtin_amdgcn_s_setprio(0);

                // ---- p = exp(s*scale - OFF), row-sum per lane, bounce via LDS ----
                bool diag = (t == qt);
#pragma unroll
                for (int jt = 0; jt < 4; jt++) {
#pragma unroll
                    for (int r = 0; r < 4; r++) {
                        int row = lg * 4 + r;
                        float pv = __expf(sC[jt][r] * scale - OFF);
                        if (diag && (kv0 + jt * 16 + lr > q0 + row)) pv = 0.f;
                        lsum[r] += pv;
                        int colb = (lr + 16 * jt) * 2;
                        *(_Float16*)(pbase + row * 128 + (colb ^ ((row & 7) << 4))) = (_Float16)pv;
                    }
                }

                // ---- wait V only; stage(t+1) stays outstanding ----
                if (hasnext) asm volatile("s_waitcnt vmcnt(4)" ::: "memory");
                else         asm volatile("s_waitcnt vmcnt(0)" ::: "memory");
                __builtin_amdgcn_sched_barrier(0);

                // ---- O += P V ----
                __builtin_amdgcn_s_setprio(1);
#pragma unroll
                for (int kk2 = 0; kk2 < 2; kk2++) {
                    half8 pa = *(const half8*)(pbase + lr * 128 +
                                               ((kk2 * 64 + lg * 16) ^ ((lr & 7) << 4)));
#pragma unroll
                    for (int jo = 0; jo < 8; jo++) {
                        half8 bv = (kk2 == 0) ? vr0[jo] : vr1[jo];
                        oacc[jo] = __builtin_amdgcn_mfma_f32_16x16x32_f16(pa, bv, oacc[jo], 0, 0, 0);
                    }
                }
                __builtin_amdgcn_s_setprio(0);
            }
        }

        // ---- lsum: 16-lane group reduce; one lane writes per row ----
#pragma unroll
        for (int r = 0; r < 4; r++) {
#pragma unroll
            for (int off = 1; off < 16; off <<= 1) lsum[r] += __shfl_xor(lsum[r], off);
        }
        if (lr == 0) {
#pragma unroll
            for (int r = 0; r < 4; r++)
                Lab[((size_t)half * NH + h) * L + q0 + lg * 4 + r] = lsum[r];
        }

        // ---- write unnormalized partial O tile (fp16, owned exclusively) ----
        _Float16* ob = Oab + (size_t)half * L * D;
#pragma unroll
        for (int jo = 0; jo < 8; jo++) {
#pragma unroll
            for (int r = 0; r < 4; r++) {
                int row = q0 + lg * 4 + r;
                int col = h * HD + jo * 16 + lr;
                ob[(size_t)row * D + col] = (_Float16)oacc[jo][r];
            }
        }
    }
}

// ---------------- normalize: aoh = fp16((Oa+Ob) / (La+Lb)) ----------------
__global__ void normalize_o(const _Float16* __restrict__ Oab, const float* __restrict__ Lab,
                            _Float16* __restrict__ out) {
    int i8 = blockIdx.x * blockDim.x + threadIdx.x;   // over L*D/8
    int row = i8 >> 8;                                 // D/8 = 256
    int c8 = (i8 & 255) << 3;
    int h = c8 >> 7;
    half8 a = reinterpret_cast<const half8*>(Oab)[i8];
    half8 b = reinterpret_cast<const half8*>(Oab + (size_t)L * D)[i8];
    float la = Lab[(size_t)h * L + row];
    float lb = Lab[(size_t)(NH + h) * L + row];
    float inv = 1.0f / (la + lb);
    half8 o;
#pragma unroll
    for (int j = 0; j < 8; j++) o[j] = (_Float16)(((float)a[j] + (float)b[j]) * inv);
    reinterpret_cast<half8*>(out)[i8] = o;
}

extern "C" void kernel_launch(void* const* d_in, const int* in_sizes, int n_in,
                              void* d_out, int out_size, void* d_ws, size_t ws_size,
                              hipStream_t stream) {
    const float* x = (const float*)d_in[0];
    const float* wqkv = (const float*)d_in[1];
    const float* wout = (const float*)d_in[2];
    // block_mask (d_in[3]) is tril(ones) == causal; handled analytically.

    _Float16* ws = (_Float16*)d_ws;
    _Float16* xh = ws;                                    // L*D
    _Float16* wqkvh = xh + (size_t)L * D;                 // 3*D*D
    _Float16* wouth = wqkvh + (size_t)3 * D * D;          // D*D
    _Float16* qkh = wouth + (size_t)D * D;                // 2*NH*L*HD
    _Float16* vth = qkh + (size_t)2 * NH * L * HD;        // NH*HD*L
    _Float16* aoh = vth + (size_t)NH * HD * L;            // L*D
    _Float16* Oab = aoh + (size_t)L * D;                  // 2*L*D fp16 partials
    float* Lab = (float*)(Oab + (size_t)2 * L * D);       // 2*NH*L f32
    int* cnt = (int*)(Lab + (size_t)2 * NH * L);          // work-queue counter

    hipMemsetAsync(cnt, 0, 256, stream);

    cvt_kernel<<<2048, 256, 0, stream>>>(x, xh, L * D / 4);
    cvt_kernel<<<2048, 256, 0, stream>>>(wqkv, wqkvh, 3 * D * D / 4);
    cvt_kernel<<<2048, 256, 0, stream>>>(wout, wouth, D * D / 4);

    gemm_nt<0><<<dim3(L / 128, 3 * D / 128), 256, 0, stream>>>(
        xh, wqkvh, nullptr, qkh, vth, L, 3 * D, D);

    norm_rope<<<2 * NH * L / 4, 256, 0, stream>>>(qkh);

    attn_kernel<<<768, 256, 0, stream>>>(qkh, vth, Oab, Lab, cnt);

    normalize_o<<<L * D / 8 / 256, 256, 0, stream>>>(Oab, Lab, aoh);

    gemm_nt<1><<<dim3(L / 128, D / 128), 256, 0, stream>>>(
        aoh, wouth, (float*)d_out, nullptr, nullptr, L, D, D);
}